// Round 1
// baseline (2811.523 us; speedup 1.0000x reference)
//
#include <hip/hip_runtime.h>
#include <hip/hip_bf16.h>
#include <cstddef>

// DimeNet++ interaction block, fp32 baseline.
// K1 k_edge_pre : x_ji = silu(m@W_ji+b), x_kj = silu((silu(m@W_kj+b)*rbf_e)@W_down), zero agg
// K2 k_msg      : sbf_e = (sbf@W_sbf1)@W_sbf2; atomicAdd(agg[dst], x_kj[src]*sbf_e)
// K3 k_post     : m_update = silu(agg@W_up)+x_ji; res_before; final; m+...; 2x res_after -> out

__device__ __forceinline__ float silu_f(float x) { return x / (1.0f + expf(-x)); }

// ---------------------------------------------------------------- K1
__global__ __launch_bounds__(256) void k_edge_pre(
    const float* __restrict__ m, const float* __restrict__ rbf,
    const float* __restrict__ W_rbf1, const float* __restrict__ W_rbf2,
    const float* __restrict__ W_ji, const float* __restrict__ b_ji,
    const float* __restrict__ W_kj, const float* __restrict__ b_kj,
    const float* __restrict__ W_down,
    float* __restrict__ x_ji, float* __restrict__ x_kj, float* __restrict__ agg)
{
    __shared__ float sT[128][66];   // activation tile, transposed [k][e]; reused
    __shared__ float rbf8[64][8];

    const int tid = threadIdx.x;
    const int eg = tid >> 5;        // 0..7  (edge group: 8 edges each)
    const int cg = tid & 31;        // 0..31 (col group)
    const int c0 = cg * 4;
    const int eb = blockIdx.x * 64;

    // stage m tile (64 edges x 128) transposed into LDS
    #pragma unroll
    for (int i = 0; i < 32; ++i) {
        int lin = i * 256 + tid;
        int c = lin & 127, e = lin >> 7;
        sT[c][e] = m[(size_t)(eb + e) * 128 + c];
    }
    // rbf8 = rbf @ W_rbf1  (64 x 8)
    #pragma unroll
    for (int i = 0; i < 2; ++i) {
        int lin = i * 256 + tid;
        int e = lin >> 3, b = lin & 7;
        float a = 0.f;
        #pragma unroll
        for (int j = 0; j < 6; ++j) a += rbf[(size_t)(eb + e) * 6 + j] * W_rbf1[j * 8 + b];
        rbf8[e][b] = a;
    }
    __syncthreads();

    // dual GEMM: m@W_ji and m@W_kj, K=128
    float accJ[8][4] = {};
    float accK[8][4] = {};
    #pragma unroll 2
    for (int k = 0; k < 128; ++k) {
        float4 bJ = *(const float4*)&W_ji[k * 128 + c0];
        float4 bK = *(const float4*)&W_kj[k * 128 + c0];
        const float2* ar = (const float2*)&sT[k][eg * 8];
        float2 a01 = ar[0], a23 = ar[1], a45 = ar[2], a67 = ar[3];
        float a[8] = {a01.x, a01.y, a23.x, a23.y, a45.x, a45.y, a67.x, a67.y};
        #pragma unroll
        for (int i = 0; i < 8; ++i) {
            accJ[i][0] += a[i] * bJ.x; accJ[i][1] += a[i] * bJ.y;
            accJ[i][2] += a[i] * bJ.z; accJ[i][3] += a[i] * bJ.w;
            accK[i][0] += a[i] * bK.x; accK[i][1] += a[i] * bK.y;
            accK[i][2] += a[i] * bK.z; accK[i][3] += a[i] * bK.w;
        }
    }

    float4 bjiv = *(const float4*)&b_ji[c0];
    float4 bkjv = *(const float4*)&b_kj[c0];
    float bkja[4] = {bkjv.x, bkjv.y, bkjv.z, bkjv.w};
    float wr2a[8][4];
    #pragma unroll
    for (int b = 0; b < 8; ++b) {
        float4 w = *(const float4*)&W_rbf2[b * 128 + c0];
        wr2a[b][0] = w.x; wr2a[b][1] = w.y; wr2a[b][2] = w.z; wr2a[b][3] = w.w;
    }
    __syncthreads();   // everyone done reading sT (m tile)

    #pragma unroll
    for (int i = 0; i < 8; ++i) {
        int e = eg * 8 + i;
        float4 xo;
        xo.x = silu_f(accJ[i][0] + bjiv.x);
        xo.y = silu_f(accJ[i][1] + bjiv.y);
        xo.z = silu_f(accJ[i][2] + bjiv.z);
        xo.w = silu_f(accJ[i][3] + bjiv.w);
        *(float4*)&x_ji[(size_t)(eb + e) * 128 + c0] = xo;

        float rb[8];
        #pragma unroll
        for (int b = 0; b < 8; ++b) rb[b] = rbf8[e][b];
        #pragma unroll
        for (int j = 0; j < 4; ++j) {
            float re = 0.f;
            #pragma unroll
            for (int b = 0; b < 8; ++b) re += rb[b] * wr2a[b][j];
            sT[c0 + j][e] = silu_f(accK[i][j] + bkja[j]) * re;  // gated H, transposed
        }
    }
    __syncthreads();

    // down-proj: (gated) @ W_down, K=128, 64 out cols
    float acc2[8][2] = {};
    const int d0 = cg * 2;
    #pragma unroll 2
    for (int k = 0; k < 128; ++k) {
        float2 bd = *(const float2*)&W_down[k * 64 + d0];
        const float2* ar = (const float2*)&sT[k][eg * 8];
        float2 a01 = ar[0], a23 = ar[1], a45 = ar[2], a67 = ar[3];
        float a[8] = {a01.x, a01.y, a23.x, a23.y, a45.x, a45.y, a67.x, a67.y};
        #pragma unroll
        for (int i = 0; i < 8; ++i) {
            acc2[i][0] += a[i] * bd.x;
            acc2[i][1] += a[i] * bd.y;
        }
    }
    #pragma unroll
    for (int i = 0; i < 8; ++i) {
        int e = eg * 8 + i;
        float2 o;
        o.x = silu_f(acc2[i][0]);
        o.y = silu_f(acc2[i][1]);
        *(float2*)&x_kj[(size_t)(eb + e) * 64 + d0] = o;
    }

    // zero agg rows for this block's 64 edges (ws is poisoned 0xAA each call)
    float4 z = {0.f, 0.f, 0.f, 0.f};
    #pragma unroll
    for (int i = 0; i < 4; ++i)
        ((float4*)agg)[(size_t)blockIdx.x * 1024 + i * 256 + tid] = z;
}

// ---------------------------------------------------------------- K2
__global__ __launch_bounds__(256) void k_msg(
    const float* __restrict__ sbf, const int* __restrict__ idx_src,
    const int* __restrict__ idx_dst,
    const float* __restrict__ W_sbf1, const float* __restrict__ W_sbf2,
    const float* __restrict__ x_kj, float* __restrict__ agg)
{
    __shared__ float sbf_s[4][64 * 42];
    __shared__ float t1_s[4][64][8];
    __shared__ float ws2_s[8][64];

    const int tid = threadIdx.x;
    const int w = tid >> 6;
    const int lane = tid & 63;

    #pragma unroll
    for (int i = 0; i < 2; ++i) {
        int idx = i * 256 + tid;                 // 0..511
        ws2_s[idx >> 6][idx & 63] = W_sbf2[idx];
    }

    const size_t tb = (size_t)blockIdx.x * 256 + (size_t)w * 64;  // wave's 64 triplets
    const float* srcp = sbf + tb * 42;
    #pragma unroll
    for (int i = 0; i < 42; ++i)
        sbf_s[w][i * 64 + lane] = srcp[(size_t)i * 64 + lane];    // contiguous copy
    __syncthreads();

    // t1 = sbf @ W_sbf1  (lane owns one triplet row)
    float t1r[8] = {0, 0, 0, 0, 0, 0, 0, 0};
    for (int j = 0; j < 42; ++j) {
        float sv = sbf_s[w][lane * 42 + j];
        #pragma unroll
        for (int b = 0; b < 8; ++b) t1r[b] += sv * W_sbf1[j * 8 + b];
    }
    #pragma unroll
    for (int b = 0; b < 8; ++b) t1_s[w][lane][b] = t1r[b];
    __syncthreads();

    int src_r = idx_src[tb + lane];
    int dst_r = idx_dst[tb + lane];
    // lane <-> INT-dim; loop triplets of this wave
    for (int t = 0; t < 64; ++t) {
        float se = 0.f;
        #pragma unroll
        for (int b = 0; b < 8; ++b) se += t1_s[w][t][b] * ws2_s[b][lane];
        int s = __shfl(src_r, t);
        int d = __shfl(dst_r, t);
        float v = x_kj[(size_t)s * 64 + lane];
        atomicAdd(&agg[(size_t)d * 64 + lane], v * se);
    }
}

// ---------------------------------------------------------------- K3
template <int K>
__device__ __forceinline__ void gemm_tile(const float (*S)[66], const float* __restrict__ W,
                                          int eg, int cg, float acc[8][4])
{
    const int c0 = cg * 4;
    #pragma unroll
    for (int i = 0; i < 8; ++i)
        #pragma unroll
        for (int j = 0; j < 4; ++j) acc[i][j] = 0.f;
    #pragma unroll 2
    for (int k = 0; k < K; ++k) {
        float4 b = *(const float4*)&W[k * 128 + c0];
        const float2* ar = (const float2*)&S[k][eg * 8];
        float2 a01 = ar[0], a23 = ar[1], a45 = ar[2], a67 = ar[3];
        float a[8] = {a01.x, a01.y, a23.x, a23.y, a45.x, a45.y, a67.x, a67.y};
        #pragma unroll
        for (int i = 0; i < 8; ++i) {
            acc[i][0] += a[i] * b.x; acc[i][1] += a[i] * b.y;
            acc[i][2] += a[i] * b.z; acc[i][3] += a[i] * b.w;
        }
    }
}

__global__ __launch_bounds__(256) void k_post(
    const float* __restrict__ agg, const float* __restrict__ x_ji,
    const float* __restrict__ m,
    const float* __restrict__ W_up,
    const float* __restrict__ Wb1, const float* __restrict__ bb1,
    const float* __restrict__ Wb2, const float* __restrict__ bb2,
    const float* __restrict__ W_final, const float* __restrict__ b_final,
    const float* __restrict__ Wa1, const float* __restrict__ ba1,
    const float* __restrict__ Wa2, const float* __restrict__ ba2,
    float* __restrict__ out)
{
    __shared__ float A[128][66];
    __shared__ float B[128][66];

    const int tid = threadIdx.x;
    const int eg = tid >> 5;
    const int cg = tid & 31;
    const int c0 = cg * 4;
    const int eb = blockIdx.x * 64;

    // stage agg tile (64 x 64) transposed into A rows 0..63
    #pragma unroll
    for (int i = 0; i < 16; ++i) {
        int lin = i * 256 + tid;
        int e = lin >> 6, d = lin & 63;
        A[d][e] = agg[(size_t)(eb + e) * 64 + d];
    }
    __syncthreads();

    float acc[8][4];

    // m_update = silu(agg @ W_up) + x_ji  -> B
    gemm_tile<64>(A, W_up, eg, cg, acc);
    #pragma unroll
    for (int i = 0; i < 8; ++i) {
        int e = eg * 8 + i;
        float4 xj = *(const float4*)&x_ji[(size_t)(eb + e) * 128 + c0];
        B[c0 + 0][e] = silu_f(acc[i][0]) + xj.x;
        B[c0 + 1][e] = silu_f(acc[i][1]) + xj.y;
        B[c0 + 2][e] = silu_f(acc[i][2]) + xj.z;
        B[c0 + 3][e] = silu_f(acc[i][3]) + xj.w;
    }
    __syncthreads();

    // res_before: h1 = silu(B@Wb1+bb1) -> A ; B += silu(A@Wb2+bb2)
    {
        gemm_tile<128>(B, Wb1, eg, cg, acc);
        float4 bv = *(const float4*)&bb1[c0];
        float ba[4] = {bv.x, bv.y, bv.z, bv.w};
        #pragma unroll
        for (int i = 0; i < 8; ++i) {
            int e = eg * 8 + i;
            #pragma unroll
            for (int j = 0; j < 4; ++j) A[c0 + j][e] = silu_f(acc[i][j] + ba[j]);
        }
        __syncthreads();
        gemm_tile<128>(A, Wb2, eg, cg, acc);
        float4 bv2 = *(const float4*)&bb2[c0];
        float ba2_[4] = {bv2.x, bv2.y, bv2.z, bv2.w};
        #pragma unroll
        for (int i = 0; i < 8; ++i) {
            int e = eg * 8 + i;
            #pragma unroll
            for (int j = 0; j < 4; ++j) B[c0 + j][e] += silu_f(acc[i][j] + ba2_[j]);
        }
        __syncthreads();
    }

    // final: A = m + silu(B@W_final + b_final)
    {
        gemm_tile<128>(B, W_final, eg, cg, acc);
        float4 bv = *(const float4*)&b_final[c0];
        float ba[4] = {bv.x, bv.y, bv.z, bv.w};
        #pragma unroll
        for (int i = 0; i < 8; ++i) {
            int e = eg * 8 + i;
            float4 mv = *(const float4*)&m[(size_t)(eb + e) * 128 + c0];
            float ma[4] = {mv.x, mv.y, mv.z, mv.w};
            #pragma unroll
            for (int j = 0; j < 4; ++j) A[c0 + j][e] = ma[j] + silu_f(acc[i][j] + ba[j]);
        }
        __syncthreads();
    }

    // 2x res_after on A
    for (int r = 0; r < 2; ++r) {
        const float* W1 = Wa1 + (size_t)r * 16384;
        const float* W2 = Wa2 + (size_t)r * 16384;
        const float* b1 = ba1 + r * 128;
        const float* b2 = ba2 + r * 128;

        gemm_tile<128>(A, W1, eg, cg, acc);
        float4 bv = *(const float4*)&b1[c0];
        float b1a[4] = {bv.x, bv.y, bv.z, bv.w};
        #pragma unroll
        for (int i = 0; i < 8; ++i) {
            int e = eg * 8 + i;
            #pragma unroll
            for (int j = 0; j < 4; ++j) B[c0 + j][e] = silu_f(acc[i][j] + b1a[j]);
        }
        __syncthreads();

        gemm_tile<128>(B, W2, eg, cg, acc);
        float4 bv2 = *(const float4*)&b2[c0];
        float b2a[4] = {bv2.x, bv2.y, bv2.z, bv2.w};
        if (r == 0) {
            #pragma unroll
            for (int i = 0; i < 8; ++i) {
                int e = eg * 8 + i;
                #pragma unroll
                for (int j = 0; j < 4; ++j) A[c0 + j][e] += silu_f(acc[i][j] + b2a[j]);
            }
            __syncthreads();
        } else {
            #pragma unroll
            for (int i = 0; i < 8; ++i) {
                int e = eg * 8 + i;
                float4 o;
                o.x = A[c0 + 0][e] + silu_f(acc[i][0] + b2a[0]);
                o.y = A[c0 + 1][e] + silu_f(acc[i][1] + b2a[1]);
                o.z = A[c0 + 2][e] + silu_f(acc[i][2] + b2a[2]);
                o.w = A[c0 + 3][e] + silu_f(acc[i][3] + b2a[3]);
                *(float4*)&out[(size_t)(eb + e) * 128 + c0] = o;
            }
        }
    }
}

// ---------------------------------------------------------------- launch
extern "C" void kernel_launch(void* const* d_in, const int* in_sizes, int n_in,
                              void* d_out, int out_size, void* d_ws, size_t ws_size,
                              hipStream_t stream)
{
    (void)n_in; (void)out_size; (void)ws_size;
    const float* m       = (const float*)d_in[0];
    const float* rbf     = (const float*)d_in[1];
    const float* sbf     = (const float*)d_in[2];
    const int*   idx_src = (const int*)d_in[3];
    const int*   idx_dst = (const int*)d_in[4];
    const float* W_rbf1  = (const float*)d_in[5];
    const float* W_rbf2  = (const float*)d_in[6];
    const float* W_sbf1  = (const float*)d_in[7];
    const float* W_sbf2  = (const float*)d_in[8];
    const float* W_ji    = (const float*)d_in[9];
    const float* b_ji    = (const float*)d_in[10];
    const float* W_kj    = (const float*)d_in[11];
    const float* b_kj    = (const float*)d_in[12];
    const float* W_down  = (const float*)d_in[13];
    const float* W_up    = (const float*)d_in[14];
    const float* Wb1     = (const float*)d_in[15];
    const float* bb1     = (const float*)d_in[16];
    const float* Wb2     = (const float*)d_in[17];
    const float* bb2     = (const float*)d_in[18];
    const float* W_final = (const float*)d_in[19];
    const float* b_final = (const float*)d_in[20];
    const float* Wa1     = (const float*)d_in[21];
    const float* ba1     = (const float*)d_in[22];
    const float* Wa2     = (const float*)d_in[23];
    const float* ba2     = (const float*)d_in[24];

    const int E = in_sizes[0] / 128;
    const int T = in_sizes[3];

    float* x_ji = (float*)d_ws;                  // E*128
    float* x_kj = x_ji + (size_t)E * 128;        // E*64
    float* agg  = x_kj + (size_t)E * 64;         // E*64
    float* out  = (float*)d_out;

    hipLaunchKernelGGL(k_edge_pre, dim3(E / 64), dim3(256), 0, stream,
                       m, rbf, W_rbf1, W_rbf2, W_ji, b_ji, W_kj, b_kj, W_down,
                       x_ji, x_kj, agg);
    hipLaunchKernelGGL(k_msg, dim3(T / 256), dim3(256), 0, stream,
                       sbf, idx_src, idx_dst, W_sbf1, W_sbf2, x_kj, agg);
    hipLaunchKernelGGL(k_post, dim3(E / 64), dim3(256), 0, stream,
                       agg, x_ji, m, W_up, Wb1, bb1, Wb2, bb2,
                       W_final, b_final, Wa1, ba1, Wa2, ba2, out);
}

// Round 3
// 1484.954 us; speedup vs baseline: 1.8933x; 1.8933x over previous
//
#include <hip/hip_runtime.h>
#include <cstddef>

// DimeNet++ interaction block — split-bf16 MFMA version.
// k_wprep : transpose+split all GEMM weights to bf16 hi/lo (B^T layout, N x K)
// k_pre   : x_ji = bf16(silu(m@W_ji+b)); gated = silu(m@W_kj+b)*rbf_e;
//           x_kj = silu(gated@W_down); zero agg        [MFMA, 64-edge tiles]
// k_msg   : sbf_e = (sbf@W_sbf1)@W_sbf2; atomicAdd(agg[dst], x_kj[src]*sbf_e)
// k_post  : full post chain (W_up, res_before, final, 2x res_after) [MFMA]
//
// Split-bf16: x = hi + lo (both bf16). a*b ~= ah*bh + ah*bl + al*bh (3 MFMA),
// dropped al*bl term ~2^-18 |a||b| — negligible vs fp32 path.

typedef __attribute__((ext_vector_type(8))) short short8;
typedef __attribute__((ext_vector_type(8))) __bf16 bfrag;
typedef __attribute__((ext_vector_type(4))) float f32x4;

#define LP 136   // LDS row pitch in bf16 elems (128 + 8 pad -> 272B rows, 16B aligned)

// weight table offsets (elements) inside wHi/wLo
#define OFF_JI   0
#define OFF_KJ   16384
#define OFF_DOWN 32768
#define OFF_UP   40960
#define OFF_B1   49152
#define OFF_B2   65536
#define OFF_FIN  81920
#define OFF_A1R0 98304
#define OFF_A1R1 114688
#define OFF_A2R0 131072
#define OFF_A2R1 147456
#define W_ELEMS  163840

__device__ __forceinline__ float silu_f(float x){ return x / (1.0f + __expf(-x)); }

__device__ __forceinline__ unsigned short f2bf(float f){   // RNE truncate to bf16
    unsigned u = __float_as_uint(f);
    return (unsigned short)((u + 0x7fffu + ((u >> 16) & 1u)) >> 16);
}
__device__ __forceinline__ float bf2f(unsigned short s){
    return __uint_as_float(((unsigned)s) << 16);
}
__device__ __forceinline__ bfrag ldfrag(const unsigned short* p){
    return __builtin_bit_cast(bfrag, *(const short8*)p);
}
__device__ __forceinline__ f32x4 mfma16(bfrag a, bfrag b, f32x4 c){
    return __builtin_amdgcn_mfma_f32_16x16x32_bf16(a, b, c, 0, 0, 0);
}

// ---- GEMM core: A [64 x Kdim] hi/lo in LDS, W^T [N x Kdim] hi/lo in global.
// Wave covers 4 M-tiles x NCOL N-tiles (cols col0/col1). 3-MFMA split product.
template<int NKT, int NCOL>
__device__ __forceinline__ void gemm_core(
    const unsigned short* aH, const unsigned short* aL,
    const unsigned short* __restrict__ wH, const unsigned short* __restrict__ wL,
    int Kdim, int col0, int col1, int lr, int lk, f32x4 acc[4][2])
{
    #pragma unroll
    for (int mt = 0; mt < 4; ++mt)
        #pragma unroll
        for (int j = 0; j < NCOL; ++j)
            #pragma unroll
            for (int q = 0; q < 4; ++q) acc[mt][j][q] = 0.f;

    const unsigned short* w0H = wH + (size_t)col0 * Kdim;
    const unsigned short* w0L = wL + (size_t)col0 * Kdim;
    const unsigned short* w1H = wH + (size_t)col1 * Kdim;
    const unsigned short* w1L = wL + (size_t)col1 * Kdim;

    #pragma unroll
    for (int kt = 0; kt < NKT; ++kt){
        const int k0 = kt * 32 + lk;
        bfrag ah[4], al[4];
        #pragma unroll
        for (int mt = 0; mt < 4; ++mt){
            ah[mt] = ldfrag(&aH[(mt*16 + lr)*LP + k0]);
            al[mt] = ldfrag(&aL[(mt*16 + lr)*LP + k0]);
        }
        #pragma unroll
        for (int j = 0; j < NCOL; ++j){
            bfrag bh = ldfrag(j == 0 ? &w0H[k0] : &w1H[k0]);
            bfrag bl = ldfrag(j == 0 ? &w0L[k0] : &w1L[k0]);
            #pragma unroll
            for (int mt = 0; mt < 4; ++mt){
                acc[mt][j] = mfma16(ah[mt], bh, acc[mt][j]);
                acc[mt][j] = mfma16(ah[mt], bl, acc[mt][j]);
                acc[mt][j] = mfma16(al[mt], bh, acc[mt][j]);
            }
        }
    }
}

// write per-lane D elements back into LDS activation buffer as hi/lo bf16
__device__ __forceinline__ void writeD(unsigned short* AH, unsigned short* AL,
    const f32x4 v[4][2], int col0, int col1, int lq)
{
    #pragma unroll
    for (int mt = 0; mt < 4; ++mt)
      #pragma unroll
      for (int j = 0; j < 2; ++j){
        const int col = j ? col1 : col0;
        #pragma unroll
        for (int r = 0; r < 4; ++r){
            const int row = mt*16 + lq + r;
            const float f = v[mt][j][r];
            const unsigned short h = f2bf(f);
            AH[row*LP + col] = h;
            AL[row*LP + col] = f2bf(f - bf2f(h));
        }
      }
}

// ---------------------------------------------------------------- weight prep
__global__ __launch_bounds__(256) void k_wprep(
    const float* __restrict__ W_ji, const float* __restrict__ W_kj,
    const float* __restrict__ W_down, const float* __restrict__ W_up,
    const float* __restrict__ Wb1, const float* __restrict__ Wb2,
    const float* __restrict__ W_final,
    const float* __restrict__ Wa1, const float* __restrict__ Wa2,
    unsigned short* __restrict__ hiB, unsigned short* __restrict__ loB)
{
    const float* src; int K, N, off;
    switch (blockIdx.y){
      case 0:  src = W_ji;        K=128; N=128; off=OFF_JI;   break;
      case 1:  src = W_kj;        K=128; N=128; off=OFF_KJ;   break;
      case 2:  src = W_down;      K=128; N=64;  off=OFF_DOWN; break;
      case 3:  src = W_up;        K=64;  N=128; off=OFF_UP;   break;
      case 4:  src = Wb1;         K=128; N=128; off=OFF_B1;   break;
      case 5:  src = Wb2;         K=128; N=128; off=OFF_B2;   break;
      case 6:  src = W_final;     K=128; N=128; off=OFF_FIN;  break;
      case 7:  src = Wa1;         K=128; N=128; off=OFF_A1R0; break;
      case 8:  src = Wa1 + 16384; K=128; N=128; off=OFF_A1R1; break;
      case 9:  src = Wa2;         K=128; N=128; off=OFF_A2R0; break;
      default: src = Wa2 + 16384; K=128; N=128; off=OFF_A2R1; break;
    }
    int lin = blockIdx.x * 256 + threadIdx.x;
    if (lin >= K * N) return;
    int n = lin / K, k = lin - n * K;
    float v = src[(size_t)k * N + n];           // W^T[n][k] = W[k][n]
    unsigned short h = f2bf(v);
    hiB[off + lin] = h;
    loB[off + lin] = f2bf(v - bf2f(h));
}

// ---------------------------------------------------------------- K1
__global__ __launch_bounds__(256, 2) void k_pre_mfma(
    const float* __restrict__ m, const float* __restrict__ rbf,
    const float* __restrict__ W_rbf1, const float* __restrict__ W_rbf2,
    const float* __restrict__ b_ji, const float* __restrict__ b_kj,
    const unsigned short* __restrict__ wHi, const unsigned short* __restrict__ wLo,
    unsigned short* __restrict__ x_ji, float* __restrict__ x_kj, float* __restrict__ agg)
{
    __shared__ unsigned short AH[64 * LP];
    __shared__ unsigned short AL[64 * LP];
    __shared__ float rbf8[64][8];

    const int tid = threadIdx.x;
    const int w = tid >> 6, l = tid & 63;
    const int lr = l & 15, lk = (l >> 4) * 8, lq = (l >> 4) * 4;
    const int eb = blockIdx.x * 64;
    const int col0 = w * 32 + lr, col1 = col0 + 16;

    // stage m tile (64x128) -> LDS hi/lo
    #pragma unroll
    for (int i = 0; i < 8; ++i){
        int lin4 = i * 256 + tid;
        int row = lin4 >> 5, c4 = (lin4 & 31) * 4;
        float4 v = *(const float4*)&m[(size_t)(eb + row) * 128 + c4];
        unsigned short h0=f2bf(v.x), h1=f2bf(v.y), h2=f2bf(v.z), h3=f2bf(v.w);
        unsigned short* ph = &AH[row*LP + c4];
        unsigned short* pl = &AL[row*LP + c4];
        ph[0]=h0; ph[1]=h1; ph[2]=h2; ph[3]=h3;
        pl[0]=f2bf(v.x-bf2f(h0)); pl[1]=f2bf(v.y-bf2f(h1));
        pl[2]=f2bf(v.z-bf2f(h2)); pl[3]=f2bf(v.w-bf2f(h3));
    }
    // rbf8 = rbf @ W_rbf1 (64 x 8)
    #pragma unroll
    for (int i = 0; i < 2; ++i){
        int lin = i * 256 + tid;
        int e = lin >> 3, b = lin & 7;
        float a = 0.f;
        #pragma unroll
        for (int j = 0; j < 6; ++j) a += rbf[(size_t)(eb + e) * 6 + j] * W_rbf1[j * 8 + b];
        rbf8[e][b] = a;
    }
    // zero agg rows (ws re-poisoned every call)
    {
        float4 z = {0.f, 0.f, 0.f, 0.f};
        #pragma unroll
        for (int i = 0; i < 4; ++i)
            ((float4*)agg)[(size_t)blockIdx.x * 1024 + i * 256 + tid] = z;
    }
    __syncthreads();

    f32x4 acc[4][2];

    // x_ji = bf16(silu(m@W_ji + b_ji))
    gemm_core<4,2>(AH, AL, wHi + OFF_JI, wLo + OFF_JI, 128, col0, col1, lr, lk, acc);
    {
        float bj0 = b_ji[col0], bj1 = b_ji[col1];
        #pragma unroll
        for (int mt = 0; mt < 4; ++mt)
          #pragma unroll
          for (int j = 0; j < 2; ++j){
            int col = j ? col1 : col0;
            float bj = j ? bj1 : bj0;
            #pragma unroll
            for (int r = 0; r < 4; ++r){
                int row = mt*16 + lq + r;
                x_ji[(size_t)(eb + row) * 128 + col] = f2bf(silu_f(acc[mt][j][r] + bj));
            }
          }
    }
    // gated = silu(m@W_kj + b_kj) * rbf_e  (rbf_e = rbf8 @ W_rbf2 inline)
    gemm_core<4,2>(AH, AL, wHi + OFF_KJ, wLo + OFF_KJ, 128, col0, col1, lr, lk, acc);
    {
        float bk0 = b_kj[col0], bk1 = b_kj[col1];
        float wc[2][8];
        #pragma unroll
        for (int b = 0; b < 8; ++b){
            wc[0][b] = W_rbf2[b * 128 + col0];
            wc[1][b] = W_rbf2[b * 128 + col1];
        }
        #pragma unroll
        for (int mt = 0; mt < 4; ++mt)
          #pragma unroll
          for (int r = 0; r < 4; ++r){
            int row = mt*16 + lq + r;
            const float4* rp = (const float4*)&rbf8[row][0];
            float4 ra = rp[0], rb = rp[1];
            #pragma unroll
            for (int j = 0; j < 2; ++j){
                float re = ra.x*wc[j][0] + ra.y*wc[j][1] + ra.z*wc[j][2] + ra.w*wc[j][3]
                         + rb.x*wc[j][4] + rb.y*wc[j][5] + rb.z*wc[j][6] + rb.w*wc[j][7];
                float bk = j ? bk1 : bk0;
                acc[mt][j][r] = silu_f(acc[mt][j][r] + bk) * re;
            }
          }
    }
    __syncthreads();          // all waves done reading m tile
    writeD(AH, AL, acc, col0, col1, lq);
    __syncthreads();

    // x_kj = silu(gated @ W_down)   (N=64: wave w owns cols w*16..w*16+15)
    {
        const int colD = w * 16 + lr;
        f32x4 ad[4][2];
        gemm_core<4,1>(AH, AL, wHi + OFF_DOWN, wLo + OFF_DOWN, 128, colD, colD, lr, lk, ad);
        #pragma unroll
        for (int mt = 0; mt < 4; ++mt)
          #pragma unroll
          for (int r = 0; r < 4; ++r){
            int row = mt*16 + lq + r;
            x_kj[(size_t)(eb + row) * 64 + colD] = silu_f(ad[mt][0][r]);
          }
    }
}

// ---------------------------------------------------------------- K2 (unchanged)
__global__ __launch_bounds__(256) void k_msg(
    const float* __restrict__ sbf, const int* __restrict__ idx_src,
    const int* __restrict__ idx_dst,
    const float* __restrict__ W_sbf1, const float* __restrict__ W_sbf2,
    const float* __restrict__ x_kj, float* __restrict__ agg)
{
    __shared__ float sbf_s[4][64 * 42];
    __shared__ float t1_s[4][64][8];
    __shared__ float ws2_s[8][64];

    const int tid = threadIdx.x;
    const int w = tid >> 6;
    const int lane = tid & 63;

    #pragma unroll
    for (int i = 0; i < 2; ++i){
        int idx = i * 256 + tid;
        ws2_s[idx >> 6][idx & 63] = W_sbf2[idx];
    }

    const size_t tb = (size_t)blockIdx.x * 256 + (size_t)w * 64;
    const float* srcp = sbf + tb * 42;
    #pragma unroll
    for (int i = 0; i < 42; ++i)
        sbf_s[w][i * 64 + lane] = srcp[(size_t)i * 64 + lane];
    __syncthreads();

    float t1r[8] = {0,0,0,0,0,0,0,0};
    for (int j = 0; j < 42; ++j){
        float sv = sbf_s[w][lane * 42 + j];
        #pragma unroll
        for (int b = 0; b < 8; ++b) t1r[b] += sv * W_sbf1[j * 8 + b];
    }
    #pragma unroll
    for (int b = 0; b < 8; ++b) t1_s[w][lane][b] = t1r[b];
    __syncthreads();

    int src_r = idx_src[tb + lane];
    int dst_r = idx_dst[tb + lane];
    for (int t = 0; t < 64; ++t){
        float se = 0.f;
        #pragma unroll
        for (int b = 0; b < 8; ++b) se += t1_s[w][t][b] * ws2_s[b][lane];
        int s = __shfl(src_r, t);
        int d = __shfl(dst_r, t);
        float v = x_kj[(size_t)s * 64 + lane];
        atomicAdd(&agg[(size_t)d * 64 + lane], v * se);
    }
}

// ---------------------------------------------------------------- K3
__global__ __launch_bounds__(256, 2) void k_post_mfma(
    const float* __restrict__ agg, const unsigned short* __restrict__ x_ji,
    const float* __restrict__ m,
    const unsigned short* __restrict__ wHi, const unsigned short* __restrict__ wLo,
    const float* __restrict__ bb1, const float* __restrict__ bb2,
    const float* __restrict__ b_final,
    const float* __restrict__ ba1, const float* __restrict__ ba2,
    float* __restrict__ out)
{
    __shared__ unsigned short AH[64 * LP];
    __shared__ unsigned short AL[64 * LP];

    const int tid = threadIdx.x;
    const int w = tid >> 6, l = tid & 63;
    const int lr = l & 15, lk = (l >> 4) * 8, lq = (l >> 4) * 4;
    const int eb = blockIdx.x * 64;
    const int col0 = w * 32 + lr, col1 = col0 + 16;

    // stage agg tile (64x64) -> LDS hi/lo (cols 0..63)
    #pragma unroll
    for (int i = 0; i < 4; ++i){
        int lin4 = i * 256 + tid;
        int row = lin4 >> 4, c4 = (lin4 & 15) * 4;
        float4 v = *(const float4*)&agg[(size_t)(eb + row) * 64 + c4];
        unsigned short h0=f2bf(v.x), h1=f2bf(v.y), h2=f2bf(v.z), h3=f2bf(v.w);
        unsigned short* ph = &AH[row*LP + c4];
        unsigned short* pl = &AL[row*LP + c4];
        ph[0]=h0; ph[1]=h1; ph[2]=h2; ph[3]=h3;
        pl[0]=f2bf(v.x-bf2f(h0)); pl[1]=f2bf(v.y-bf2f(h1));
        pl[2]=f2bf(v.z-bf2f(h2)); pl[3]=f2bf(v.w-bf2f(h3));
    }
    __syncthreads();

    f32x4 acc[4][2], res[4][2];

    // S1: u0 = silu(agg@W_up) + x_ji   (keep u0 in res regs)
    gemm_core<2,2>(AH, AL, wHi + OFF_UP, wLo + OFF_UP, 64, col0, col1, lr, lk, acc);
    #pragma unroll
    for (int mt = 0; mt < 4; ++mt)
      #pragma unroll
      for (int j = 0; j < 2; ++j){
        int col = j ? col1 : col0;
        #pragma unroll
        for (int r = 0; r < 4; ++r){
            int row = mt*16 + lq + r;
            res[mt][j][r] = silu_f(acc[mt][j][r]) + bf2f(x_ji[(size_t)(eb + row) * 128 + col]);
        }
      }
    __syncthreads();
    writeD(AH, AL, res, col0, col1, lq);
    __syncthreads();

#define H_STAGE(OFF, BIAS)                                                        \
    gemm_core<4,2>(AH, AL, wHi + (OFF), wLo + (OFF), 128, col0, col1, lr, lk, acc); \
    {   float b0_ = (BIAS)[col0], b1_ = (BIAS)[col1];                             \
        _Pragma("unroll")                                                         \
        for (int mt = 0; mt < 4; ++mt){                                           \
            _Pragma("unroll")                                                     \
            for (int r = 0; r < 4; ++r){                                          \
                acc[mt][0][r] = silu_f(acc[mt][0][r] + b0_);                      \
                acc[mt][1][r] = silu_f(acc[mt][1][r] + b1_);                      \
            }                                                                     \
        }                                                                         \
    }                                                                             \
    __syncthreads(); writeD(AH, AL, acc, col0, col1, lq); __syncthreads();

#define R_STAGE(OFF, BIAS)                                                        \
    gemm_core<4,2>(AH, AL, wHi + (OFF), wLo + (OFF), 128, col0, col1, lr, lk, acc); \
    {   float b0_ = (BIAS)[col0], b1_ = (BIAS)[col1];                             \
        _Pragma("unroll")                                                         \
        for (int mt = 0; mt < 4; ++mt){                                           \
            _Pragma("unroll")                                                     \
            for (int r = 0; r < 4; ++r){                                          \
                res[mt][0][r] += silu_f(acc[mt][0][r] + b0_);                     \
                res[mt][1][r] += silu_f(acc[mt][1][r] + b1_);                     \
            }                                                                     \
        }                                                                         \
    }                                                                             \
    __syncthreads(); writeD(AH, AL, res, col0, col1, lq); __syncthreads();

    // res_before
    H_STAGE(OFF_B1, bb1)
    R_STAGE(OFF_B2, bb2)

    // final: f = m + silu(u1@W_final + b_final)
    gemm_core<4,2>(AH, AL, wHi + OFF_FIN, wLo + OFF_FIN, 128, col0, col1, lr, lk, acc);
    {
        float b0_ = b_final[col0], b1_ = b_final[col1];
        #pragma unroll
        for (int mt = 0; mt < 4; ++mt)
          #pragma unroll
          for (int j = 0; j < 2; ++j){
            int col = j ? col1 : col0;
            float bv = j ? b1_ : b0_;
            #pragma unroll
            for (int r = 0; r < 4; ++r){
                int row = mt*16 + lq + r;
                res[mt][j][r] = m[(size_t)(eb + row) * 128 + col] + silu_f(acc[mt][j][r] + bv);
            }
          }
    }
    __syncthreads();
    writeD(AH, AL, res, col0, col1, lq);
    __syncthreads();

    // res_after r0
    H_STAGE(OFF_A1R0, ba1)
    R_STAGE(OFF_A2R0, ba2)

    // res_after r1
    H_STAGE(OFF_A1R1, ba1 + 128)

    // last GEMM: out = res + silu(h@Wa2[1] + ba2[1])
    gemm_core<4,2>(AH, AL, wHi + OFF_A2R1, wLo + OFF_A2R1, 128, col0, col1, lr, lk, acc);
    {
        float b0_ = ba2[128 + col0], b1_ = ba2[128 + col1];
        #pragma unroll
        for (int mt = 0; mt < 4; ++mt)
          #pragma unroll
          for (int j = 0; j < 2; ++j){
            int col = j ? col1 : col0;
            float bv = j ? b1_ : b0_;
            #pragma unroll
            for (int r = 0; r < 4; ++r){
                int row = mt*16 + lq + r;
                out[(size_t)(eb + row) * 128 + col] = res[mt][j][r] + silu_f(acc[mt][j][r] + bv);
            }
          }
    }
#undef H_STAGE
#undef R_STAGE
}

// ---------------------------------------------------------------- launch
extern "C" void kernel_launch(void* const* d_in, const int* in_sizes, int n_in,
                              void* d_out, int out_size, void* d_ws, size_t ws_size,
                              hipStream_t stream)
{
    (void)n_in; (void)out_size; (void)ws_size;
    const float* m       = (const float*)d_in[0];
    const float* rbf     = (const float*)d_in[1];
    const float* sbf     = (const float*)d_in[2];
    const int*   idx_src = (const int*)d_in[3];
    const int*   idx_dst = (const int*)d_in[4];
    const float* W_rbf1  = (const float*)d_in[5];
    const float* W_rbf2  = (const float*)d_in[6];
    const float* W_sbf1  = (const float*)d_in[7];
    const float* W_sbf2  = (const float*)d_in[8];
    const float* W_ji    = (const float*)d_in[9];
    const float* b_ji    = (const float*)d_in[10];
    const float* W_kj    = (const float*)d_in[11];
    const float* b_kj    = (const float*)d_in[12];
    const float* W_down  = (const float*)d_in[13];
    const float* W_up    = (const float*)d_in[14];
    const float* Wb1     = (const float*)d_in[15];
    const float* bb1     = (const float*)d_in[16];
    const float* Wb2     = (const float*)d_in[17];
    const float* bb2     = (const float*)d_in[18];
    const float* W_final = (const float*)d_in[19];
    const float* b_final = (const float*)d_in[20];
    const float* Wa1     = (const float*)d_in[21];
    const float* ba1     = (const float*)d_in[22];
    const float* Wa2     = (const float*)d_in[23];
    const float* ba2     = (const float*)d_in[24];

    const int E = in_sizes[0] / 128;
    const int T = in_sizes[3];

    // ws layout: x_ji bf16 E*128 | x_kj f32 E*64 | agg f32 E*64 | wHi | wLo
    unsigned short* x_ji = (unsigned short*)d_ws;
    float* x_kj = (float*)(x_ji + (size_t)E * 128);
    float* agg  = x_kj + (size_t)E * 64;
    unsigned short* wHi = (unsigned short*)(agg + (size_t)E * 64);
    unsigned short* wLo = wHi + W_ELEMS;
    float* out = (float*)d_out;

    hipLaunchKernelGGL(k_wprep, dim3(64, 11), dim3(256), 0, stream,
                       W_ji, W_kj, W_down, W_up, Wb1, Wb2, W_final, Wa1, Wa2, wHi, wLo);
    hipLaunchKernelGGL(k_pre_mfma, dim3(E / 64), dim3(256), 0, stream,
                       m, rbf, W_rbf1, W_rbf2, b_ji, b_kj, wHi, wLo, x_ji, x_kj, agg);
    hipLaunchKernelGGL(k_msg, dim3(T / 256), dim3(256), 0, stream,
                       sbf, idx_src, idx_dst, W_sbf1, W_sbf2, x_kj, agg);
    hipLaunchKernelGGL(k_post_mfma, dim3(E / 64), dim3(256), 0, stream,
                       agg, x_ji, m, wHi, wLo, bb1, bb2, b_final, ba1, ba2, out);
}